// Round 9
// baseline (244.145 us; speedup 1.0000x reference)
//
#include <hip/hip_runtime.h>
#include <math.h>

#define B_    4
#define E_    50000
#define CIN_  32
#define CO_   64
#define EPS_  1e-5f
#define NB1_  256                  // conv1 blocks/batch (grid 1024 ≈ 4 blocks/CU, LDS cap)
#define NB2_  384                  // conv2 blocks/batch (grid 1536 ≈ 6 blocks/CU, LDS cap)
#define NT_   ((E_ + 63) / 64)     // 64-edge tiles per batch (transpose grids)

typedef __attribute__((ext_vector_type(8))) short  s16x8;
typedef __attribute__((ext_vector_type(4))) float  f32x4;
typedef unsigned short u16;

__device__ __forceinline__ u16 f2bf(float f) {
    unsigned u = __builtin_bit_cast(unsigned, f);
    u += 0x7fffu + ((u >> 16) & 1u);      // round-to-nearest-even
    return (u16)(u >> 16);
}
__device__ __forceinline__ float bf2f(u16 h) {
    return __builtin_bit_cast(float, (unsigned)h << 16);
}

// ------------------------------------------------------------------
// ws layout:
//   [0, B*E*64) u16        x1 (channel-last bf16; fet [B][E][32] aliases it)
//   [B*E*64, 2*B*E*64) u16 y  (conv output, bf16 channel-last)
//   + 3*512 floats         st[3] (per-layer (b,c) sum/sumsq; zeroed by
//                          k_transpose_in block 0 — no memset dispatches)
// ------------------------------------------------------------------

// fe fp32 [B][CIN][E] -> fet bf16 [B][E][CIN]; block (0,0) also zeroes st[3]
__global__ __launch_bounds__(256) void k_transpose_in(
    const float* __restrict__ fe, u16* __restrict__ fet, float* __restrict__ st)
{
    if (blockIdx.x == 0 && blockIdx.y == 0)
        for (int i = threadIdx.x; i < 3 * 512; i += 256) st[i] = 0.f;

    __shared__ float t[CIN_][65];
    const int b = blockIdx.y;
    const int e0 = blockIdx.x * 64;
    for (int idx = threadIdx.x; idx < CIN_ * 64; idx += 256) {
        int c = idx >> 6, el = idx & 63, e = e0 + el;
        t[c][el] = (e < E_) ? fe[((size_t)b * CIN_ + c) * E_ + e] : 0.f;
    }
    __syncthreads();
    for (int idx = threadIdx.x; idx < 64 * CIN_; idx += 256) {
        int el = idx >> 5, c = idx & 31, e = e0 + el;   // CIN_ == 32
        if (e < E_) fet[((size_t)b * E_ + e) * CIN_ + c] = f2bf(t[c][el]);
    }
}

// MFMA mesh-conv, bf16 activations (R8 structure; tile-stride now runtime
// `nblk` so the grid can be sized to the per-kernel LDS residency cap).
// Per tile: [gather + feat build -> LDS] SYNC [MFMA + epilogue -> ytile] SYNC
// [coalesced ytile -> y store] SYNC.  Wave w owns o = w*16+(l&15);
// XCD-pinned batches (id&7 in {2b,2b+1}).  W staged once per block in
// NPASS passes (smem-size invariant pinned by static_asserts).
template<int C, int EDG>
__global__ __launch_bounds__(256, 4) void k_conv_mfma(
    const u16* __restrict__ xt, const int* __restrict__ ei,
    const float* __restrict__ W, const float* __restrict__ bias,
    u16* __restrict__ y, float* __restrict__ st, int nblk)
{
    constexpr int K   = 5 * C;                 // 160 / 320
    constexpr int KF  = K / 32;                // 5 / 10
    constexpr int SL  = ((K / 8) + 7) & ~7;    // 16B slots per feat row
    constexpr int TPE = 256 / EDG;             // builder threads per edge
    constexpr int LG  = (TPE == 4) ? 2 : 3;
    static_assert(C / TPE == 8, "one s16x8 per builder thread");
    constexpr int MF  = EDG / 16;              // M-fragments per tile
    constexpr int NTt = (E_ + EDG - 1) / EDG;  // tiles per batch
    constexpr int YP  = 72;                    // padded ytile row (u16)

    constexpr int SMEM_U16 = EDG * SL * 8;
    constexpr int NPASS = (CO_ * K > SMEM_U16) ? 2 : 1;  // W-staging passes
    constexpr int WR    = CO_ / NPASS;                   // W rows per pass
    static_assert(WR * K <= SMEM_U16, "W staging pass must fit in smem");
    static_assert(WR % 8 == 0, "row-swizzle needs 8-row alignment");
    static_assert((WR * K) % 4 == 0, "float4 staging");

    __shared__ alignas(16) u16 smem[SMEM_U16];
    __shared__ alignas(16) u16 ytile[EDG * YP];

    const int id  = blockIdx.x;
    const int xcd = id & 7;
    const int b   = xcd >> 1;
    const int j   = ((id >> 3) << 1) | (xcd & 1);   // [0, nblk)

    const int t = threadIdx.x;
    const int w = t >> 6;
    const int l = t & 63;

    // ---- phase 0+1 (once per block, NPASS passes): stage W fp32 [O][C][5]
    //      -> LDS bf16 [o][k], k=s*C+c, 16B slots XOR-swizzled by (o&7);
    //      each wave pulls its B-fragments from the pass holding its rows ----
    s16x8 bw[KF];
    const int o = w * 16 + (l & 15);
#pragma unroll
    for (int p = 0; p < NPASS; ++p) {
        const float4* Wp = reinterpret_cast<const float4*>(W + (size_t)p * WR * K);
        for (int i4 = t; i4 < WR * K / 4; i4 += 256) {
            const float4 v = Wp[i4];
            const float vv[4] = {v.x, v.y, v.z, v.w};
#pragma unroll
            for (int jj = 0; jj < 4; ++jj) {
                const int idx = i4 * 4 + jj;          // = (ol*C + c)*5 + s
                const int ol  = idx / (C * 5);        // local row in this pass
                const int rem = idx - ol * (C * 5);
                const int c   = rem / 5;
                const int s   = rem - c * 5;
                const int el  = ol * K + s * C + c;
                const int adr = (((el >> 3) ^ (ol & 7)) << 3) | (el & 7);
                smem[adr] = f2bf(vv[jj]);
            }
        }
        __syncthreads();
        if (o >= p * WR && o < (p + 1) * WR) {
            const int lo = o - p * WR;
#pragma unroll
            for (int kf = 0; kf < KF; ++kf) {
                const int el  = lo * K + kf * 32 + (l >> 4) * 8;
                const int adr = (((el >> 3) ^ (lo & 7)) << 3);
                bw[kf] = *reinterpret_cast<const s16x8*>(smem + adr);
            }
        }
        __syncthreads();
    }
    const float bv = bias[o];
    float sacc = 0.f, ssacc = 0.f;

    const u16* xb = xt + (size_t)b * E_ * C;
    u16* ybase = y + (size_t)b * E_ * CO_;
    const int* ei_b = ei + (size_t)b * E_ * 4;

    const int m = t >> LG;            // builder edge within tile
    const int q = t & (TPE - 1);
    const int cb = q * 8;             // channel chunk

    // ---- tile loop ----
#pragma unroll 1
    for (int tt = j; tt < NTt; tt += nblk) {
        const int e0 = tt * EDG;
        const int e  = e0 + m;
        const bool valid = e < E_;

        // gather + feat build -> LDS
        {
            int4 nb;
            if (valid) nb = *reinterpret_cast<const int4*>(ei_b + (size_t)e * 4);
            else { nb.x = 0; nb.y = 0; nb.z = 0; nb.w = 0; }
            s16x8 fo[5];
            if (valid) {
                const u16* re = xb + (size_t)e    * C;
                const u16* r1 = xb + (size_t)nb.x * C;
                const u16* r2 = xb + (size_t)nb.y * C;
                const u16* r3 = xb + (size_t)nb.z * C;
                const u16* r4 = xb + (size_t)nb.w * C;
                const s16x8 xe = *reinterpret_cast<const s16x8*>(re + cb);
                const s16x8 a1 = *reinterpret_cast<const s16x8*>(r1 + cb);
                const s16x8 a2 = *reinterpret_cast<const s16x8*>(r2 + cb);
                const s16x8 a3 = *reinterpret_cast<const s16x8*>(r3 + cb);
                const s16x8 a4 = *reinterpret_cast<const s16x8*>(r4 + cb);
                fo[0] = xe;                           // identity feat: exact copy
#pragma unroll
                for (int d = 0; d < 8; ++d) {
                    const float v1 = bf2f((u16)a1[d]);
                    const float v2 = bf2f((u16)a2[d]);
                    const float v3 = bf2f((u16)a3[d]);
                    const float v4 = bf2f((u16)a4[d]);
                    fo[1][d] = (short)f2bf(v1 + v3);
                    fo[2][d] = (short)f2bf(v2 + v4);
                    fo[3][d] = (short)f2bf(fabsf(v1 - v3));
                    fo[4][d] = (short)f2bf(fabsf(v2 - v4));
                }
            } else {
#pragma unroll
                for (int s = 0; s < 5; ++s) fo[s] = s16x8{0,0,0,0,0,0,0,0};
            }
#pragma unroll
            for (int s = 0; s < 5; ++s) {
                const int in_slot = (s * C + cb) >> 3;
                const int adr = (m * SL + (in_slot ^ (m & 7))) << 3;
                *reinterpret_cast<s16x8*>(smem + adr) = fo[s];
            }
        }
        __syncthreads();

        // MFMA + epilogue -> ytile (bf16), stats in regs
#pragma unroll
        for (int mf = 0; mf < MF; ++mf) {
            f32x4 acc = f32x4{0.f, 0.f, 0.f, 0.f};
            const int ma = mf * 16 + (l & 15);
#pragma unroll
            for (int kf = 0; kf < KF; ++kf) {
                const int slot = kf * 4 + (l >> 4);
                const int adr  = (ma * SL + (slot ^ (ma & 7))) << 3;
                const s16x8 a  = *reinterpret_cast<const s16x8*>(smem + adr);
                acc = __builtin_amdgcn_mfma_f32_16x16x32_bf16(a, bw[kf], acc, 0, 0, 0);
            }
#pragma unroll
            for (int r = 0; r < 4; ++r) {
                const int mm = mf * 16 + (l >> 4) * 4 + r;
                const float v = acc[r] + bv;
                ytile[mm * YP + o] = f2bf(v);
                if (e0 + mm < E_) { sacc += v; ssacc += v * v; }
            }
        }
        __syncthreads();

        // coalesced store ytile -> y
        for (int idx = t; idx < EDG * 8; idx += 256) {
            const int row = idx >> 3, c8 = idx & 7;
            if (e0 + row < E_)
                *reinterpret_cast<s16x8*>(ybase + (size_t)(e0 + row) * CO_ + c8 * 8) =
                    *reinterpret_cast<const s16x8*>(ytile + row * YP + c8 * 8);
        }
        __syncthreads();
    }

    // ---- block-level stats flush ----
    sacc  += __shfl_xor(sacc, 16);  ssacc += __shfl_xor(ssacc, 16);
    sacc  += __shfl_xor(sacc, 32);  ssacc += __shfl_xor(ssacc, 32);
    if (l < 16) {
        atomicAdd(&st[(b * CO_ + o) * 2 + 0], sacc);
        atomicAdd(&st[(b * CO_ + o) * 2 + 1], ssacc);
    }
}

// x1 = relu((y-m)*rs [+ x1]); m/rs computed inline from st (bf16 I/O)
template<bool ADD>
__global__ __launch_bounds__(256) void k_norm(
    const u16* __restrict__ y, const float* __restrict__ st,
    u16* __restrict__ x1)
{
    constexpr float invE = 1.f / E_;
    const size_t total8 = (size_t)B_ * E_ * CO_ / 8;
    for (size_t i8 = (size_t)blockIdx.x * 256 + threadIdx.x; i8 < total8;
         i8 += (size_t)gridDim.x * 256) {
        const size_t i = i8 * 8;
        const int b = (int)(i / ((size_t)E_ * CO_));
        const int c = (int)(i & 63);          // multiple of 8
        const s16x8 yv = reinterpret_cast<const s16x8*>(y)[i8];
        s16x8 xv;
        if (ADD) xv = reinterpret_cast<const s16x8*>(x1)[i8];
        const float4* stp = reinterpret_cast<const float4*>(st + ((size_t)b * CO_ + c) * 2);
        s16x8 ov;
#pragma unroll
        for (int d2 = 0; d2 < 4; ++d2) {
            const float4 s2 = stp[d2];        // (sum,sumsq) x2 channels
            const float m0 = s2.x * invE, v0 = s2.y * invE - m0 * m0;
            const float m1 = s2.z * invE, v1 = s2.w * invE - m1 * m1;
            float a0 = (bf2f((u16)yv[d2*2])   - m0) * rsqrtf(v0 + EPS_);
            float a1 = (bf2f((u16)yv[d2*2+1]) - m1) * rsqrtf(v1 + EPS_);
            if (ADD) { a0 += bf2f((u16)xv[d2*2]); a1 += bf2f((u16)xv[d2*2+1]); }
            ov[d2*2]   = (short)f2bf(fmaxf(a0, 0.f));
            ov[d2*2+1] = (short)f2bf(fmaxf(a1, 0.f));
        }
        reinterpret_cast<s16x8*>(x1)[i8] = ov;
    }
}

// final block: out[b][c][e] = relu((y-m)*rs + x1)  (fused norm+residual+transpose)
__global__ __launch_bounds__(256) void k_norm_t(
    const u16* __restrict__ y, const float* __restrict__ st,
    const u16* __restrict__ x1, float* __restrict__ out)
{
    __shared__ float tt[CO_][65];
    constexpr float invE = 1.f / E_;
    const int b  = blockIdx.y;
    const int e0 = blockIdx.x * 64;
    const int t  = threadIdx.x;
    for (int idx = t; idx < 512; idx += 256) {
        const int el = idx >> 3, c = (idx & 7) * 8;
        const int e  = e0 + el;
        if (e < E_) {
            const size_t base = ((size_t)b * E_ + e) * CO_ + c;
            const s16x8 yv = *reinterpret_cast<const s16x8*>(y  + base);
            const s16x8 xv = *reinterpret_cast<const s16x8*>(x1 + base);
            const float4* stp = reinterpret_cast<const float4*>(st + ((size_t)b * CO_ + c) * 2);
#pragma unroll
            for (int d2 = 0; d2 < 4; ++d2) {
                const float4 s2 = stp[d2];
                const float m0 = s2.x * invE, v0 = s2.y * invE - m0 * m0;
                const float m1 = s2.z * invE, v1 = s2.w * invE - m1 * m1;
                const float a0 = (bf2f((u16)yv[d2*2])   - m0) * rsqrtf(v0 + EPS_) + bf2f((u16)xv[d2*2]);
                const float a1 = (bf2f((u16)yv[d2*2+1]) - m1) * rsqrtf(v1 + EPS_) + bf2f((u16)xv[d2*2+1]);
                tt[c + d2*2][el]     = fmaxf(a0, 0.f);
                tt[c + d2*2 + 1][el] = fmaxf(a1, 0.f);
            }
        }
    }
    __syncthreads();
    for (int idx = t; idx < 1024; idx += 256) {
        const int c = idx >> 4, seg = idx & 15;
        const int e = e0 + seg * 4;
        float* op = out + ((size_t)b * CO_ + c) * E_;
        if (e + 3 < E_) {
            float4 v = {tt[c][seg*4], tt[c][seg*4+1], tt[c][seg*4+2], tt[c][seg*4+3]};
            *reinterpret_cast<float4*>(op + e) = v;
        } else {
#pragma unroll
            for (int k2 = 0; k2 < 4; ++k2)
                if (e + k2 < E_) op[e + k2] = tt[c][seg*4 + k2];
        }
    }
}

extern "C" void kernel_launch(void* const* d_in, const int* in_sizes, int n_in,
                              void* d_out, int out_size, void* d_ws, size_t ws_size,
                              hipStream_t stream)
{
    const float* fe = (const float*)d_in[0];
    const int*   ei = (const int*)  d_in[1];
    const float* W1 = (const float*)d_in[2];
    const float* b1 = (const float*)d_in[3];
    const float* W2 = (const float*)d_in[4];
    const float* b2 = (const float*)d_in[5];

    u16*   x1  = (u16*)d_ws;                          // [B][E][64] bf16
    u16*   y   = x1 + (size_t)B_ * E_ * CO_;          // [B][E][64] bf16
    float* st  = (float*)(y + (size_t)B_ * E_ * CO_); // 3 x [B][64][2]
    u16*   fet = x1;                                  // fe_t aliases x1 (dead after conv1)
    float* out = (float*)d_out;

    const dim3 blk(256);
    const dim3 gT(NT_, B_);
    const dim3 gC1(NB1_ * B_);
    const dim3 gC2(NB2_ * B_);

    k_transpose_in<<<gT, blk, 0, stream>>>(fe, fet, st);   // also zeroes st[3]

    k_conv_mfma<CIN_, 64><<<gC1, blk, 0, stream>>>(fet, ei, W1, b1, y, st, NB1_);
    k_norm<false><<<2048, blk, 0, stream>>>(y, st, x1);

    k_conv_mfma<CO_, 32><<<gC2, blk, 0, stream>>>(x1, ei, W2, b2, y, st + 512, NB2_);
    k_norm<true><<<2048, blk, 0, stream>>>(y, st + 512, x1);

    k_conv_mfma<CO_, 32><<<gC2, blk, 0, stream>>>(x1, ei, W2 + (size_t)CO_ * CO_ * 5,
                                                  b2 + CO_, y, st + 1024, NB2_);
    k_norm_t<<<gT, blk, 0, stream>>>(y, st + 1024, x1, out);
}

// Round 10
// 237.475 us; speedup vs baseline: 1.0281x; 1.0281x over previous
//
#include <hip/hip_runtime.h>
#include <math.h>

#define B_    4
#define E_    50000
#define CIN_  32
#define CO_   64
#define EPS_  1e-5f
#define NB1_  256                  // conv1 blocks/batch
#define NB2_  384                  // conv2 blocks/batch
#define NT_   ((E_ + 63) / 64)     // 64-edge tiles per batch (transpose grids)

typedef __attribute__((ext_vector_type(8))) short  s16x8;
typedef __attribute__((ext_vector_type(4))) float  f32x4;
typedef unsigned short u16;

__device__ __forceinline__ u16 f2bf(float f) {
    unsigned u = __builtin_bit_cast(unsigned, f);
    u += 0x7fffu + ((u >> 16) & 1u);      // round-to-nearest-even
    return (u16)(u >> 16);
}
__device__ __forceinline__ float bf2f(u16 h) {
    return __builtin_bit_cast(float, (unsigned)h << 16);
}

// ------------------------------------------------------------------
// ws layout:
//   [0, B*E*64) u16        x1 (channel-last bf16; fet [B][E][32] aliases it)
//   [B*E*64, 2*B*E*64) u16 y  (conv output, bf16 channel-last)
//   + 3*512 floats         st[3] (per-layer (b,c) sum/sumsq; zeroed by
//                          k_transpose_in block 0)
//   + 51200 u16            wpre: W pre-converted to bf16 in swizzled-LDS
//                          element order (layer1 10240 | layer2a 20480 |
//                          layer2b 20480) -> per-block staging is a
//                          straight contiguous copy (no conflicts).
// ------------------------------------------------------------------

// Pre-permute one W element: input [o][c][s] fp32 -> swizzled bf16 order.
// Must match k_conv_mfma's staging/pull mapping exactly.
template<int C, int WR>
__device__ __forceinline__ void prep_one(
    const float* __restrict__ W, u16* __restrict__ dst, int idx)
{
    constexpr int K = 5 * C;
    const int o   = idx / (C * 5);
    const int rem = idx - o * (C * 5);
    const int c   = rem / 5;
    const int s   = rem - c * 5;
    const int p   = o / WR;
    const int ol  = o - p * WR;
    const int el  = ol * K + s * C + c;
    const int adr = (((el >> 3) ^ (ol & 7)) << 3) | (el & 7);
    dst[p * WR * K + adr] = f2bf(W[idx]);
}

__global__ __launch_bounds__(256) void k_prep_w(
    const float* __restrict__ W1, const float* __restrict__ W2,
    u16* __restrict__ wpre)
{
    const int gid = blockIdx.x * 256 + threadIdx.x;
    if (gid < 10240)       prep_one<CIN_, 64>(W1, wpre, gid);                       // conv1
    else if (gid < 30720)  prep_one<CO_, 32>(W2, wpre + 10240, gid - 10240);        // conv2 blk0
    else if (gid < 51200)  prep_one<CO_, 32>(W2 + 20480, wpre + 30720, gid - 30720);// conv2 blk1
}

// fe fp32 [B][CIN][E] -> fet bf16 [B][E][CIN]; block (0,0) also zeroes st[3]
__global__ __launch_bounds__(256) void k_transpose_in(
    const float* __restrict__ fe, u16* __restrict__ fet, float* __restrict__ st)
{
    if (blockIdx.x == 0 && blockIdx.y == 0)
        for (int i = threadIdx.x; i < 3 * 512; i += 256) st[i] = 0.f;

    __shared__ float t[CIN_][65];
    const int b = blockIdx.y;
    const int e0 = blockIdx.x * 64;
    for (int idx = threadIdx.x; idx < CIN_ * 64; idx += 256) {
        int c = idx >> 6, el = idx & 63, e = e0 + el;
        t[c][el] = (e < E_) ? fe[((size_t)b * CIN_ + c) * E_ + e] : 0.f;
    }
    __syncthreads();
    for (int idx = threadIdx.x; idx < 64 * CIN_; idx += 256) {
        int el = idx >> 5, c = idx & 31, e = e0 + el;   // CIN_ == 32
        if (e < E_) fet[((size_t)b * E_ + e) * CIN_ + c] = f2bf(t[c][el]);
    }
}

// MFMA mesh-conv, bf16 activations.  W arrives pre-permuted bf16 (wpre),
// so per-block LDS staging is a contiguous s16x8 copy (R9 lesson: the
// scattered fp32->bf16 swizzle staging was ~all the bank conflicts and
// scaled with block count).  Per tile: [gather+feat build] SYNC
// [MFMA+epilogue->ytile] SYNC [coalesced store] SYNC.
// Wave w owns o = w*16+(l&15); XCD-pinned batches (id&7 in {2b,2b+1}).
template<int C, int EDG>
__global__ __launch_bounds__(256, 4) void k_conv_mfma(
    const u16* __restrict__ xt, const int* __restrict__ ei,
    const u16* __restrict__ wpre, const float* __restrict__ bias,
    u16* __restrict__ y, float* __restrict__ st, int nblk)
{
    constexpr int K   = 5 * C;                 // 160 / 320
    constexpr int KF  = K / 32;                // 5 / 10
    constexpr int SL  = ((K / 8) + 7) & ~7;    // 16B slots per feat row
    constexpr int TPE = 256 / EDG;             // builder threads per edge
    constexpr int LG  = (TPE == 4) ? 2 : 3;
    static_assert(C / TPE == 8, "one s16x8 per builder thread");
    constexpr int MF  = EDG / 16;              // M-fragments per tile
    constexpr int NTt = (E_ + EDG - 1) / EDG;  // tiles per batch
    constexpr int YP  = 72;                    // padded ytile row (u16)

    constexpr int SMEM_U16 = EDG * SL * 8;
    constexpr int NPASS = (CO_ * K > SMEM_U16) ? 2 : 1;  // W-staging passes
    constexpr int WR    = CO_ / NPASS;                   // W rows per pass
    static_assert(WR * K <= SMEM_U16, "W staging pass must fit in smem");
    static_assert(WR % 8 == 0, "row-swizzle needs 8-row alignment");
    static_assert((WR * K) % 8 == 0, "s16x8 staging");

    __shared__ alignas(16) u16 smem[SMEM_U16];
    __shared__ alignas(16) u16 ytile[EDG * YP];

    const int id  = blockIdx.x;
    const int xcd = id & 7;
    const int b   = xcd >> 1;
    const int j   = ((id >> 3) << 1) | (xcd & 1);   // [0, nblk)

    const int t = threadIdx.x;
    const int w = t >> 6;
    const int l = t & 63;

    // ---- phase 0+1 (once per block): contiguous copy of pre-permuted W
    //      into LDS, then pull this wave's B-fragments ----
    s16x8 bw[KF];
    const int o = w * 16 + (l & 15);
#pragma unroll
    for (int p = 0; p < NPASS; ++p) {
        const s16x8* Wp = reinterpret_cast<const s16x8*>(wpre + p * WR * K);
        s16x8* sm8 = reinterpret_cast<s16x8*>(smem);
        for (int i = t; i < WR * K / 8; i += 256) sm8[i] = Wp[i];
        __syncthreads();
        if (o >= p * WR && o < (p + 1) * WR) {
            const int lo = o - p * WR;
#pragma unroll
            for (int kf = 0; kf < KF; ++kf) {
                const int el  = lo * K + kf * 32 + (l >> 4) * 8;
                const int adr = (((el >> 3) ^ (lo & 7)) << 3);
                bw[kf] = *reinterpret_cast<const s16x8*>(smem + adr);
            }
        }
        __syncthreads();
    }
    const float bv = bias[o];
    float sacc = 0.f, ssacc = 0.f;

    const u16* xb = xt + (size_t)b * E_ * C;
    u16* ybase = y + (size_t)b * E_ * CO_;
    const int* ei_b = ei + (size_t)b * E_ * 4;

    const int m = t >> LG;            // builder edge within tile
    const int q = t & (TPE - 1);
    const int cb = q * 8;             // channel chunk

    // ---- tile loop ----
#pragma unroll 1
    for (int tt = j; tt < NTt; tt += nblk) {
        const int e0 = tt * EDG;
        const int e  = e0 + m;
        const bool valid = e < E_;

        // gather + feat build -> LDS
        {
            int4 nb;
            if (valid) nb = *reinterpret_cast<const int4*>(ei_b + (size_t)e * 4);
            else { nb.x = 0; nb.y = 0; nb.z = 0; nb.w = 0; }
            s16x8 fo[5];
            if (valid) {
                const u16* re = xb + (size_t)e    * C;
                const u16* r1 = xb + (size_t)nb.x * C;
                const u16* r2 = xb + (size_t)nb.y * C;
                const u16* r3 = xb + (size_t)nb.z * C;
                const u16* r4 = xb + (size_t)nb.w * C;
                const s16x8 xe = *reinterpret_cast<const s16x8*>(re + cb);
                const s16x8 a1 = *reinterpret_cast<const s16x8*>(r1 + cb);
                const s16x8 a2 = *reinterpret_cast<const s16x8*>(r2 + cb);
                const s16x8 a3 = *reinterpret_cast<const s16x8*>(r3 + cb);
                const s16x8 a4 = *reinterpret_cast<const s16x8*>(r4 + cb);
                fo[0] = xe;                           // identity feat: exact copy
#pragma unroll
                for (int d = 0; d < 8; ++d) {
                    const float v1 = bf2f((u16)a1[d]);
                    const float v2 = bf2f((u16)a2[d]);
                    const float v3 = bf2f((u16)a3[d]);
                    const float v4 = bf2f((u16)a4[d]);
                    fo[1][d] = (short)f2bf(v1 + v3);
                    fo[2][d] = (short)f2bf(v2 + v4);
                    fo[3][d] = (short)f2bf(fabsf(v1 - v3));
                    fo[4][d] = (short)f2bf(fabsf(v2 - v4));
                }
            } else {
#pragma unroll
                for (int s = 0; s < 5; ++s) fo[s] = s16x8{0,0,0,0,0,0,0,0};
            }
#pragma unroll
            for (int s = 0; s < 5; ++s) {
                const int in_slot = (s * C + cb) >> 3;
                const int adr = (m * SL + (in_slot ^ (m & 7))) << 3;
                *reinterpret_cast<s16x8*>(smem + adr) = fo[s];
            }
        }
        __syncthreads();

        // MFMA + epilogue -> ytile (bf16), stats in regs
#pragma unroll
        for (int mf = 0; mf < MF; ++mf) {
            f32x4 acc = f32x4{0.f, 0.f, 0.f, 0.f};
            const int ma = mf * 16 + (l & 15);
#pragma unroll
            for (int kf = 0; kf < KF; ++kf) {
                const int slot = kf * 4 + (l >> 4);
                const int adr  = (ma * SL + (slot ^ (ma & 7))) << 3;
                const s16x8 a  = *reinterpret_cast<const s16x8*>(smem + adr);
                acc = __builtin_amdgcn_mfma_f32_16x16x32_bf16(a, bw[kf], acc, 0, 0, 0);
            }
#pragma unroll
            for (int r = 0; r < 4; ++r) {
                const int mm = mf * 16 + (l >> 4) * 4 + r;
                const float v = acc[r] + bv;
                ytile[mm * YP + o] = f2bf(v);
                if (e0 + mm < E_) { sacc += v; ssacc += v * v; }
            }
        }
        __syncthreads();

        // coalesced store ytile -> y
        for (int idx = t; idx < EDG * 8; idx += 256) {
            const int row = idx >> 3, c8 = idx & 7;
            if (e0 + row < E_)
                *reinterpret_cast<s16x8*>(ybase + (size_t)(e0 + row) * CO_ + c8 * 8) =
                    *reinterpret_cast<const s16x8*>(ytile + row * YP + c8 * 8);
        }
        __syncthreads();
    }

    // ---- block-level stats flush ----
    sacc  += __shfl_xor(sacc, 16);  ssacc += __shfl_xor(ssacc, 16);
    sacc  += __shfl_xor(sacc, 32);  ssacc += __shfl_xor(ssacc, 32);
    if (l < 16) {
        atomicAdd(&st[(b * CO_ + o) * 2 + 0], sacc);
        atomicAdd(&st[(b * CO_ + o) * 2 + 1], ssacc);
    }
}

// x1 = relu((y-m)*rs [+ x1]); m/rs computed inline from st (bf16 I/O)
template<bool ADD>
__global__ __launch_bounds__(256) void k_norm(
    const u16* __restrict__ y, const float* __restrict__ st,
    u16* __restrict__ x1)
{
    constexpr float invE = 1.f / E_;
    const size_t total8 = (size_t)B_ * E_ * CO_ / 8;
    for (size_t i8 = (size_t)blockIdx.x * 256 + threadIdx.x; i8 < total8;
         i8 += (size_t)gridDim.x * 256) {
        const size_t i = i8 * 8;
        const int b = (int)(i / ((size_t)E_ * CO_));
        const int c = (int)(i & 63);          // multiple of 8
        const s16x8 yv = reinterpret_cast<const s16x8*>(y)[i8];
        s16x8 xv;
        if (ADD) xv = reinterpret_cast<const s16x8*>(x1)[i8];
        const float4* stp = reinterpret_cast<const float4*>(st + ((size_t)b * CO_ + c) * 2);
        s16x8 ov;
#pragma unroll
        for (int d2 = 0; d2 < 4; ++d2) {
            const float4 s2 = stp[d2];        // (sum,sumsq) x2 channels
            const float m0 = s2.x * invE, v0 = s2.y * invE - m0 * m0;
            const float m1 = s2.z * invE, v1 = s2.w * invE - m1 * m1;
            float a0 = (bf2f((u16)yv[d2*2])   - m0) * rsqrtf(v0 + EPS_);
            float a1 = (bf2f((u16)yv[d2*2+1]) - m1) * rsqrtf(v1 + EPS_);
            if (ADD) { a0 += bf2f((u16)xv[d2*2]); a1 += bf2f((u16)xv[d2*2+1]); }
            ov[d2*2]   = (short)f2bf(fmaxf(a0, 0.f));
            ov[d2*2+1] = (short)f2bf(fmaxf(a1, 0.f));
        }
        reinterpret_cast<s16x8*>(x1)[i8] = ov;
    }
}

// final block: out[b][c][e] = relu((y-m)*rs + x1)  (fused norm+residual+transpose)
__global__ __launch_bounds__(256) void k_norm_t(
    const u16* __restrict__ y, const float* __restrict__ st,
    const u16* __restrict__ x1, float* __restrict__ out)
{
    __shared__ float tt[CO_][65];
    constexpr float invE = 1.f / E_;
    const int b  = blockIdx.y;
    const int e0 = blockIdx.x * 64;
    const int t  = threadIdx.x;
    for (int idx = t; idx < 512; idx += 256) {
        const int el = idx >> 3, c = (idx & 7) * 8;
        const int e  = e0 + el;
        if (e < E_) {
            const size_t base = ((size_t)b * E_ + e) * CO_ + c;
            const s16x8 yv = *reinterpret_cast<const s16x8*>(y  + base);
            const s16x8 xv = *reinterpret_cast<const s16x8*>(x1 + base);
            const float4* stp = reinterpret_cast<const float4*>(st + ((size_t)b * CO_ + c) * 2);
#pragma unroll
            for (int d2 = 0; d2 < 4; ++d2) {
                const float4 s2 = stp[d2];
                const float m0 = s2.x * invE, v0 = s2.y * invE - m0 * m0;
                const float m1 = s2.z * invE, v1 = s2.w * invE - m1 * m1;
                const float a0 = (bf2f((u16)yv[d2*2])   - m0) * rsqrtf(v0 + EPS_) + bf2f((u16)xv[d2*2]);
                const float a1 = (bf2f((u16)yv[d2*2+1]) - m1) * rsqrtf(v1 + EPS_) + bf2f((u16)xv[d2*2+1]);
                tt[c + d2*2][el]     = fmaxf(a0, 0.f);
                tt[c + d2*2 + 1][el] = fmaxf(a1, 0.f);
            }
        }
    }
    __syncthreads();
    for (int idx = t; idx < 1024; idx += 256) {
        const int c = idx >> 4, seg = idx & 15;
        const int e = e0 + seg * 4;
        float* op = out + ((size_t)b * CO_ + c) * E_;
        if (e + 3 < E_) {
            float4 v = {tt[c][seg*4], tt[c][seg*4+1], tt[c][seg*4+2], tt[c][seg*4+3]};
            *reinterpret_cast<float4*>(op + e) = v;
        } else {
#pragma unroll
            for (int k2 = 0; k2 < 4; ++k2)
                if (e + k2 < E_) op[e + k2] = tt[c][seg*4 + k2];
        }
    }
}

extern "C" void kernel_launch(void* const* d_in, const int* in_sizes, int n_in,
                              void* d_out, int out_size, void* d_ws, size_t ws_size,
                              hipStream_t stream)
{
    const float* fe = (const float*)d_in[0];
    const int*   ei = (const int*)  d_in[1];
    const float* W1 = (const float*)d_in[2];
    const float* b1 = (const float*)d_in[3];
    const float* W2 = (const float*)d_in[4];
    const float* b2 = (const float*)d_in[5];

    u16*   x1  = (u16*)d_ws;                          // [B][E][64] bf16
    u16*   y   = x1 + (size_t)B_ * E_ * CO_;          // [B][E][64] bf16
    float* st  = (float*)(y + (size_t)B_ * E_ * CO_); // 3 x [B][64][2]
    u16*   wpre = (u16*)(st + 3 * 512);               // 51200 u16 pre-permuted W
    u16*   fet = x1;                                  // fe_t aliases x1 (dead after conv1)
    float* out = (float*)d_out;

    const dim3 blk(256);
    const dim3 gT(NT_, B_);
    const dim3 gC1(NB1_ * B_);
    const dim3 gC2(NB2_ * B_);

    k_prep_w<<<200, blk, 0, stream>>>(W1, W2, wpre);
    k_transpose_in<<<gT, blk, 0, stream>>>(fe, fet, st);   // also zeroes st[3]

    k_conv_mfma<CIN_, 64><<<gC1, blk, 0, stream>>>(fet, ei, wpre, b1, y, st, NB1_);
    k_norm<false><<<2048, blk, 0, stream>>>(y, st, x1);

    k_conv_mfma<CO_, 32><<<gC2, blk, 0, stream>>>(x1, ei, wpre + 10240, b2, y, st + 512, NB2_);
    k_norm<true><<<2048, blk, 0, stream>>>(y, st + 512, x1);

    k_conv_mfma<CO_, 32><<<gC2, blk, 0, stream>>>(x1, ei, wpre + 30720,
                                                  b2 + CO_, y, st + 1024, NB2_);
    k_norm_t<<<gT, blk, 0, stream>>>(y, st + 1024, x1, out);
}